// Round 9
// baseline (186.245 us; speedup 1.0000x reference)
//
#include <hip/hip_runtime.h>
#include <hip/hip_bf16.h>
#include <cmath>

// Problem constants
#define BATCH   4096
#define NUNITS  1024
#define INSIZE  512
#define SIGSZ   6
#define KSIG    (NUNITS * SIGSZ)          // 6144
#define SAVED   (KSIG + NUNITS)           // 7168
#define KTOT    (INSIZE + KSIG + NUNITS)  // 7680
#define OUTW    (NUNITS * (SIGSZ + 1))    // 7168
#define NKT     (KTOT / 128)              // 60

// Workspace layout (ushort elements)
#define WS_AX 0LL
#define WS_AS 2097152LL
#define WS_AT 27262976LL
#define WS_BW 31457280LL
#define WS_BU 31981568LL
#define WS_ELEMS 39321600LL
#define WS_BYTES (WS_ELEMS * 2)           // 78,643,200

typedef __attribute__((ext_vector_type(8))) short bf16x8;
typedef __attribute__((ext_vector_type(8))) unsigned short u16x8;
typedef __attribute__((ext_vector_type(4))) float f32x4;

__device__ __forceinline__ unsigned short f2bf(float f) {
    union { float f; unsigned int u; } c; c.f = f;
    unsigned int u = c.u;
    return (unsigned short)((u + 0x7FFFu + ((u >> 16) & 1u)) >> 16);  // RNE
}
__device__ __forceinline__ float bf2f(unsigned short h) {
    union { unsigned int u; float f; } c; c.u = ((unsigned int)h) << 16;
    return c.f;
}

// XOR-swizzled LDS index (ushort units), 128B (64 bf16) rows.
__device__ __forceinline__ int swz(int row, int bytecol) {
    return row * 64 + (((bytecol) ^ ((row & 7) << 4)) >> 1);
}

// ---------------- prepass: fp32 -> packed bf16 in ws ----------------
__global__ __launch_bounds__(256)
void prepack(const float* __restrict__ x, const float* __restrict__ sigs,
             const float* __restrict__ states, const float* __restrict__ Ww,
             const float* __restrict__ Uw, unsigned short* __restrict__ ws)
{
    const long long stride = (long long)gridDim.x * blockDim.x;
    for (long long p = (long long)blockIdx.x * blockDim.x + threadIdx.x;
         p < 4915200LL; p += stride) {
        const float* src; unsigned short* dst; long long o;
        if (p < 262144LL)       { src = x;      dst = ws + WS_AX; o = p; }
        else if (p < 3407872LL) { src = sigs;   dst = ws + WS_AS; o = p - 262144LL; }
        else if (p < 3932160LL) { src = states; dst = ws + WS_AT; o = p - 3407872LL; }
        else if (p < 3997696LL) { src = Ww;     dst = ws + WS_BW; o = p - 3932160LL; }
        else                    { src = Uw;     dst = ws + WS_BU; o = p - 3997696LL; }
        // nt loads: fp32 inputs are not re-read (except states, small) -> don't pollute L3
        const f32x4 v0 = __builtin_nontemporal_load((const f32x4*)(src + o * 8));
        const f32x4 v1 = __builtin_nontemporal_load((const f32x4*)(src + o * 8) + 1);
        u16x8 h;
        h[0] = f2bf(v0[0]); h[1] = f2bf(v0[1]); h[2] = f2bf(v0[2]); h[3] = f2bf(v0[3]);
        h[4] = f2bf(v1[0]); h[5] = f2bf(v1[1]); h[6] = f2bf(v1[2]); h[7] = f2bf(v1[3]);
        *(u16x8*)(dst + o * 8) = h;
    }
}

// ---------------- main GEMM + fused sigjoin ----------------
// 128x128 tile, BK=128 (two 64-col sub-tiles), 1024 threads = 16 waves:
// 2(M) x 2(N) x 4(K32-slot). Wave tile 64x64 per K-slot: 8 ds_read -> 16 MFMA.
// Grid 256 = 1 block/CU; bn = blockIdx&7 = XCD id (B-slice L2-resident).
// Ring-2 (128 KB LDS), counted vmcnt(4); per iter: wait/barrier, ds_read,
// lgkmcnt(0)+barrier, STAGE(kt+2) into the just-read buffer, MFMA.
// Epilogue: K-split-4 merged into padded 128x132 fp32 LDS tile, then dense
// nontemporal float4 store pass (full lines, no RMW, no L3 pollution).
#define GLD_LDS(G, L) __builtin_amdgcn_global_load_lds(                        \
        (const __attribute__((address_space(1))) unsigned int*)(G),           \
        (__attribute__((address_space(3))) unsigned int*)(L), 16, 0, 0)

__global__ __launch_bounds__(1024, 1)
void rsig_gemm(const unsigned short* __restrict__ ws,
               const float* __restrict__ states,
               const float* __restrict__ Wb,
               const float* __restrict__ Ub,
               const float* __restrict__ lt,
               float* __restrict__ out)
{
    // per buffer (64 KB = 32768 ushorts): A-lo [0,8192) A-hi [8192,16384)
    //                                     B-lo [16384,24576) B-hi [24576,32768)
    __shared__ unsigned short lds[2 * 32768];   // 128 KB

    const int t  = threadIdx.x;
    const int bn = blockIdx.x & 7;   // natural round-robin: same bn -> same XCD
    const int bm = blockIdx.x >> 3;  // 0..31

    const int lane = t & 63;
    const int w    = t >> 6;        // 0..15
    const int wm   = w >> 3;        // M half
    const int wn   = (w >> 2) & 1;  // N half
    const int wk   = w & 3;         // K32 slot within BK=128
    const int lr   = lane & 15;
    const int lg   = lane >> 4;

    const unsigned short* wsAx = ws + WS_AX;
    const unsigned short* wsAs = ws + WS_AS;
    const unsigned short* wsAt = ws + WS_AT;
    const unsigned short* wsBw = ws + WS_BW;
    const unsigned short* wsBu = ws + WS_BU;

    // staging: per wave 4 gld_lds (A-lo, A-hi, B-lo, B-hi), group w (8 rows x 64)
    const int sRow = lane >> 3;
    const int sCol = 8 * ((lane & 7) ^ sRow);   // pre-swizzled source col (elems)
    const int rowg = w * 8 + sRow;
    // per-lane, loop-invariant source offsets per segment (elems)
    const int loAx = rowg * INSIZE + sCol;
    const int loAs = rowg * KSIG   + sCol;
    const int loAt = rowg * NUNITS + sCol;
    const int loBw = rowg * INSIZE + sCol;
    const int loBu = rowg * SAVED  + sCol;

    f32x4 acc[4][4];
#pragma unroll
    for (int m = 0; m < 4; ++m)
#pragma unroll
        for (int n = 0; n < 4; ++n)
            acc[m][n] = (f32x4)0.f;

#define STAGE(BUF, KT)                                                                   \
    {                                                                                    \
        const int kt_ = (KT);                                                            \
        const unsigned short* abase; long long asg; int la;                              \
        if (kt_ < 4)       { abase = wsAx; asg = (long long)bm*128*INSIZE + kt_*128;       la = loAx; } \
        else if (kt_ < 52) { abase = wsAs; asg = (long long)bm*128*KSIG  + kt_*128 - 512;  la = loAs; } \
        else               { abase = wsAt; asg = (long long)bm*128*NUNITS+ kt_*128 - 6656; la = loAt; } \
        const unsigned short* bbase; long long bsg; int lb;                              \
        if (kt_ < 4)       { bbase = wsBw; bsg = (long long)bn*128*INSIZE + kt_*128;       lb = loBw; } \
        else               { bbase = wsBu; bsg = (long long)bn*128*SAVED + kt_*128 - 512;  lb = loBu; } \
        unsigned short* base = &lds[(BUF) * 32768];                                      \
        GLD_LDS(abase + asg + la,      base +         w * 512);                          \
        GLD_LDS(abase + asg + la + 64, base +  8192 + w * 512);                          \
        GLD_LDS(bbase + bsg + lb,      base + 16384 + w * 512);                          \
        GLD_LDS(bbase + bsg + lb + 64, base + 24576 + w * 512);                          \
    }

    // Prologue: 2 tiles in flight (8 loads/wave outstanding)
    STAGE(0, 0);
    STAGE(1, 1);

    for (int kt = 0; kt < NKT; ++kt) {
        // tile kt landed; tile kt+1's 4 loads stay in flight
        if (kt < NKT - 1) { asm volatile("s_waitcnt vmcnt(4)" ::: "memory"); }
        else              { asm volatile("s_waitcnt vmcnt(0)" ::: "memory"); }
        __builtin_amdgcn_s_barrier();
        __builtin_amdgcn_sched_barrier(0);

        const int cur = kt & 1;
        const unsigned short* aT = &lds[cur * 32768 + (wk >> 1) * 8192];
        const unsigned short* bT = aT + 16384;
        const int bc = (wk & 1) * 64 + lg * 16;

        bf16x8 af[4], bfr[4];
#pragma unroll
        for (int m = 0; m < 4; ++m)
            af[m] = *(const bf16x8*)&aT[swz(wm * 64 + m * 16 + lr, bc)];
#pragma unroll
        for (int n = 0; n < 4; ++n)
            bfr[n] = *(const bf16x8*)&bT[swz(wn * 64 + n * 16 + lr, bc)];

        // my reads done -> safe for everyone to overwrite this buffer after barrier
        asm volatile("s_waitcnt lgkmcnt(0)" ::: "memory");
        __builtin_amdgcn_sched_barrier(0);
        __builtin_amdgcn_s_barrier();

        if (kt + 2 < NKT) STAGE(cur, kt + 2);   // DMA flies across MFMA + next iter

#pragma unroll
        for (int m = 0; m < 4; ++m)
#pragma unroll
            for (int n = 0; n < 4; ++n)
                acc[m][n] = __builtin_amdgcn_mfma_f32_16x16x32_bf16(af[m], bfr[n], acc[m][n], 0, 0, 0);
    }

    __syncthreads();

    // ---- Phase 1: raw(+bias) -> padded LDS tile; K-split-4 merged ----
    float* rawt = (float*)lds;            // 128 rows x 132 floats (67.6 KB)
#pragma unroll
    for (int slot = 0; slot < 4; ++slot) {
        if (wk == slot) {
#pragma unroll
            for (int n = 0; n < 4; ++n) {
                const int cc = wn * 64 + n * 16 + lr;
#pragma unroll
                for (int m = 0; m < 4; ++m) {
                    const int rr = wm * 64 + m * 16 + lg * 4;
                    if (slot == 0) {
                        const float bias = Wb[bn * 128 + cc] + Ub[bn * 128 + cc];
#pragma unroll
                        for (int i = 0; i < 4; ++i)
                            rawt[(rr + i) * 132 + cc] = acc[m][n][i] + bias;
                    } else {
#pragma unroll
                        for (int i = 0; i < 4; ++i)
                            rawt[(rr + i) * 132 + cc] += acc[m][n][i];
                    }
                }
            }
        }
        __syncthreads();
    }

    // ---- Phase 2: dense nontemporal float4 store pass ----
    // per row: c in [0,192) -> sig float4; [192,224) -> raw float4.
    const float tl = expf(lt[0]);
    const int r0 = t >> 8;      // 0..3
    const int c  = t & 255;

    for (int pass = 0; pass < 32; ++pass) {
        const int r = pass * 4 + r0;
        const long long b = (long long)bm * 128 + r;
        if (c < 192) {
            const int u  = (2 * c) / 3;
            const int cs = c % 3;
            const unsigned short* srow = wsAs + b * KSIG + bn * 768;
            const float* strow = states + b * NUNITS + bn * 128;
            const ushort4 sin = *(const ushort4*)(srow + c * 4);
            const float e0 = bf2f(sin.x), e1 = bf2f(sin.y);
            const float e2 = bf2f(sin.z), e3 = bf2f(sin.w);
            f32x4 o;
            if (cs == 0) {                 // cols 6u+0..3: s0,s1,s2,s3
                const float d = rawt[r * 132 + u] - strow[u];
                o[0] = e0 + d;
                o[1] = e1 + tl;
                o[2] = e2 + d  * (0.5f * d  + e0);
                o[3] = e3 + tl * (0.5f * d  + e0);
            } else if (cs == 1) {          // cols 6u+4,5, 6(u+1)+0,1
                const float d  = rawt[r * 132 + u]     - strow[u];
                const float dn = rawt[r * 132 + u + 1] - strow[u + 1];
                const float s1 = bf2f(srow[u * 6 + 1]);
                o[0] = e0 + d  * (0.5f * tl + s1);
                o[1] = e1 + tl * (0.5f * tl + s1);
                o[2] = e2 + dn;
                o[3] = e3 + tl;
            } else {                       // cols 6u+2..5: s2,s3,s4,s5
                const float d = rawt[r * 132 + u] - strow[u];
                const unsigned int sv = *(const unsigned int*)(srow + u * 6);
                const float s0 = bf2f((unsigned short)(sv & 0xffffu));
                const float s1 = bf2f((unsigned short)(sv >> 16));
                o[0] = e0 + d  * (0.5f * d  + s0);
                o[1] = e1 + tl * (0.5f * d  + s0);
                o[2] = e2 + d  * (0.5f * tl + s1);
                o[3] = e3 + tl * (0.5f * tl + s1);
            }
            __builtin_nontemporal_store(o, (f32x4*)(out + b * OUTW + bn * 768 + c * 4));
        } else if (c < 224) {
            const int cc = (c - 192) * 4;
            const f32x4 rv = *(const f32x4*)&rawt[r * 132 + cc];
            __builtin_nontemporal_store(rv, (f32x4*)(out + b * OUTW + KSIG + bn * 128 + cc));
        }
    }
#undef STAGE
}

extern "C" void kernel_launch(void* const* d_in, const int* in_sizes, int n_in,
                              void* d_out, int out_size, void* d_ws, size_t ws_size,
                              hipStream_t stream) {
    const float* x      = (const float*)d_in[0];
    const float* sigs   = (const float*)d_in[1];
    const float* states = (const float*)d_in[2];
    const float* Ww     = (const float*)d_in[3];
    const float* Wb     = (const float*)d_in[4];
    const float* Uw     = (const float*)d_in[5];
    const float* Ub     = (const float*)d_in[6];
    const float* lt     = (const float*)d_in[7];
    float* out = (float*)d_out;

    unsigned short* ws = (unsigned short*)d_ws;
    hipLaunchKernelGGL(prepack, dim3(2048), dim3(256), 0, stream,
                       x, sigs, states, Ww, Uw, ws);
    hipLaunchKernelGGL(rsig_gemm, dim3(256), dim3(1024), 0, stream,
                       ws, states, Wb, Ub, lt, out);
}

// Round 10
// 179.045 us; speedup vs baseline: 1.0402x; 1.0402x over previous
//
#include <hip/hip_runtime.h>
#include <hip/hip_bf16.h>
#include <cmath>

// Problem constants
#define BATCH   4096
#define NUNITS  1024
#define INSIZE  512
#define SIGSZ   6
#define KSIG    (NUNITS * SIGSZ)          // 6144
#define SAVED   (KSIG + NUNITS)           // 7168
#define KTOT    (INSIZE + KSIG + NUNITS)  // 7680
#define OUTW    (NUNITS * (SIGSZ + 1))    // 7168
#define NKT     (KTOT / 128)              // 60

// Workspace layout (ushort elements)
#define WS_AX 0LL
#define WS_AS 2097152LL
#define WS_AT 27262976LL
#define WS_BW 31457280LL
#define WS_BU 31981568LL
#define WS_ELEMS 39321600LL
#define WS_BYTES (WS_ELEMS * 2)           // 78,643,200

typedef __attribute__((ext_vector_type(8)))  short bf16x8;
typedef __attribute__((ext_vector_type(8)))  unsigned short u16x8;
typedef __attribute__((ext_vector_type(4)))  float f32x4;
typedef __attribute__((ext_vector_type(16))) float f32x16;

__device__ __forceinline__ unsigned short f2bf(float f) {
    union { float f; unsigned int u; } c; c.f = f;
    unsigned int u = c.u;
    return (unsigned short)((u + 0x7FFFu + ((u >> 16) & 1u)) >> 16);  // RNE
}
__device__ __forceinline__ float bf2f(unsigned short h) {
    union { unsigned int u; float f; } c; c.u = ((unsigned int)h) << 16;
    return c.f;
}

// ---------------- prepass: fp32 -> packed bf16 in ws ----------------
// nt LOADS (fp32 streams are read-once: don't let them evict ws from L3);
// plain stores (ws must stay L3-resident for the GEMM).
__global__ __launch_bounds__(256)
void prepack(const float* __restrict__ x, const float* __restrict__ sigs,
             const float* __restrict__ states, const float* __restrict__ Ww,
             const float* __restrict__ Uw, unsigned short* __restrict__ ws)
{
    const long long stride = (long long)gridDim.x * blockDim.x;
    for (long long p = (long long)blockIdx.x * blockDim.x + threadIdx.x;
         p < 4915200LL; p += stride) {
        const float* src; unsigned short* dst; long long o;
        if (p < 262144LL)       { src = x;      dst = ws + WS_AX; o = p; }
        else if (p < 3407872LL) { src = sigs;   dst = ws + WS_AS; o = p - 262144LL; }
        else if (p < 3932160LL) { src = states; dst = ws + WS_AT; o = p - 3407872LL; }
        else if (p < 3997696LL) { src = Ww;     dst = ws + WS_BW; o = p - 3932160LL; }
        else                    { src = Uw;     dst = ws + WS_BU; o = p - 3997696LL; }
        const f32x4 v0 = __builtin_nontemporal_load((const f32x4*)(src + o * 8));
        const f32x4 v1 = __builtin_nontemporal_load((const f32x4*)(src + o * 8) + 1);
        u16x8 h;
        h[0] = f2bf(v0[0]); h[1] = f2bf(v0[1]); h[2] = f2bf(v0[2]); h[3] = f2bf(v0[3]);
        h[4] = f2bf(v1[0]); h[5] = f2bf(v1[1]); h[6] = f2bf(v1[2]); h[7] = f2bf(v1[3]);
        *(u16x8*)(dst + o * 8) = h;
    }
}

// ---------------- main GEMM + fused sigjoin ----------------
// 128x128 tile, BK=128, 1024 threads = 16 waves: 2(M) x 2(N) x 4(K32-slot).
// mfma_f32_32x32x16_bf16, wave tile 64x64 per K32 slot: 8 ds_read -> 8 MFMA
// (2x FLOP/LDS-read vs 16x16). LDS rows are 256B (16 swizzle slots): XOR with
// (row&15) -> 32-row column reads are 2-way (free). Ring-2 (128 KB), ONE
// barrier + vmcnt(0) per iter, STAGE(kt+1) issued right after the barrier.
// Epilogue: K-split-4 merge into padded 128x132 fp32 LDS tile, dense float4
// store pass (full lines, no RMW).
#define GLD_LDS(G, L) __builtin_amdgcn_global_load_lds(                        \
        (const __attribute__((address_space(1))) unsigned int*)(G),           \
        (__attribute__((address_space(3))) unsigned int*)(L), 16, 0, 0)

__global__ __launch_bounds__(1024, 1)
void rsig_gemm(const unsigned short* __restrict__ ws,
               const float* __restrict__ states,
               const float* __restrict__ Wb,
               const float* __restrict__ Ub,
               const float* __restrict__ lt,
               float* __restrict__ out)
{
    // per buffer (64 KB = 32768 ushorts): A [0,16384), B [16384,32768)
    // A layout: 128 rows x 16 slots x 8 bf16; slot s of row r holds source
    // k-block (s ^ (r&15)).
    __shared__ unsigned short lds[2 * 32768];   // 128 KB

    const int t  = threadIdx.x;
    const int bn = blockIdx.x & 7;   // natural round-robin: same bn -> same XCD
    const int bm = blockIdx.x >> 3;  // 0..31

    const int lane = t & 63;
    const int w    = t >> 6;        // 0..15
    const int wm   = w >> 3;        // M half
    const int wn   = (w >> 2) & 1;  // N half
    const int wk   = w & 3;         // K32 slot within BK=128
    const int lrow = lane & 31;
    const int lhk  = lane >> 5;     // 0..1

    const unsigned short* wsAx = ws + WS_AX;
    const unsigned short* wsAs = ws + WS_AS;
    const unsigned short* wsAt = ws + WS_AT;
    const unsigned short* wsBw = ws + WS_BW;
    const unsigned short* wsBu = ws + WS_BU;

    // staging lane decomposition: instruction covers 4 rows x 16 slots
    const int sR4 = lane >> 4;      // row-in-group 0..3
    const int sS  = lane & 15;      // slot 0..15

    f32x16 acc[2][2];
#pragma unroll
    for (int m = 0; m < 2; ++m)
#pragma unroll
        for (int n = 0; n < 2; ++n)
            acc[m][n] = (f32x16)0.f;

    // 4 gld_lds per wave per STAGE (2 A-groups + 2 B-groups; group = 4 rows)
#define STAGE(BUF, KT)                                                                   \
    {                                                                                    \
        const int kt_ = (KT);                                                            \
        const unsigned short* abase; int astr; long long koff;                           \
        if (kt_ < 4)       { abase = wsAx; astr = INSIZE; koff = (long long)kt_*128; }   \
        else if (kt_ < 52) { abase = wsAs; astr = KSIG;   koff = (long long)kt_*128-512; }\
        else               { abase = wsAt; astr = NUNITS; koff = (long long)kt_*128-6656;}\
        const unsigned short* bbase; int bstr; long long koffb;                          \
        if (kt_ < 4)       { bbase = wsBw; bstr = INSIZE; koffb = (long long)kt_*128; }  \
        else               { bbase = wsBu; bstr = SAVED;  koffb = (long long)kt_*128-512;}\
        unsigned short* base = &lds[(BUF) * 32768];                                      \
        _Pragma("unroll")                                                                \
        for (int j = 0; j < 2; ++j) {                                                    \
            const int g    = 2 * w + j;                                                  \
            const int rT   = g * 4 + sR4;                                                \
            const int cblk = sS ^ (((g & 3) << 2) | sR4);                                \
            const unsigned short* ga = abase + (size_t)(bm * 128 + rT) * astr + koff + cblk * 8; \
            GLD_LDS(ga, base + g * 512);                                                 \
            const unsigned short* gb = bbase + (size_t)(bn * 128 + rT) * bstr + koffb + cblk * 8; \
            GLD_LDS(gb, base + 16384 + g * 512);                                         \
        }                                                                                \
    }

    // Prologue: tile 0 in flight
    STAGE(0, 0);

    for (int kt = 0; kt < NKT; ++kt) {
        // my 4 loads for tile kt must have landed; all waves ditto -> barrier
        asm volatile("s_waitcnt vmcnt(0)" ::: "memory");
        __builtin_amdgcn_s_barrier();
        __builtin_amdgcn_sched_barrier(0);

        const int cur = kt & 1;
        if (kt + 1 < NKT) STAGE(cur ^ 1, kt + 1);  // DMA flies across reads+MFMA

        const unsigned short* aT = &lds[cur * 32768];
        const unsigned short* bT = aT + 16384;

        bf16x8 af[2][2], bfr[2][2];
#pragma unroll
        for (int m = 0; m < 2; ++m) {
            const int row = wm * 64 + m * 32 + lrow;
#pragma unroll
            for (int kk = 0; kk < 2; ++kk) {
                const int sg = wk * 4 + kk * 2 + lhk;
                af[m][kk] = *(const bf16x8*)&aT[row * 128 + ((sg ^ (row & 15)) << 3)];
            }
        }
#pragma unroll
        for (int n = 0; n < 2; ++n) {
            const int row = wn * 64 + n * 32 + lrow;
#pragma unroll
            for (int kk = 0; kk < 2; ++kk) {
                const int sg = wk * 4 + kk * 2 + lhk;
                bfr[n][kk] = *(const bf16x8*)&bT[row * 128 + ((sg ^ (row & 15)) << 3)];
            }
        }

#pragma unroll
        for (int kk = 0; kk < 2; ++kk)
#pragma unroll
            for (int m = 0; m < 2; ++m)
#pragma unroll
                for (int n = 0; n < 2; ++n)
                    acc[m][n] = __builtin_amdgcn_mfma_f32_32x32x16_bf16(
                        af[m][kk], bfr[n][kk], acc[m][n], 0, 0, 0);
    }

    __syncthreads();   // everyone done reading LDS before rawt reuse

    // ---- Phase 1: raw(+bias) -> padded LDS tile; K-split-4 merged ----
    // 32x32 C/D layout: col = lane&31, row = (reg&3) + 8*(reg>>2) + 4*(lane>>5)
    float* rawt = (float*)lds;            // 128 rows x 132 floats (67.6 KB)
    const int ccol   = lane & 31;
    const int rowoff = 4 * lhk;
    if (wk == 0) {
#pragma unroll
        for (int m = 0; m < 2; ++m)
#pragma unroll
            for (int n = 0; n < 2; ++n) {
                const int cc = wn * 64 + n * 32 + ccol;
                const int rr = wm * 64 + m * 32 + rowoff;
                const float bias = Wb[bn * 128 + cc] + Ub[bn * 128 + cc];
#pragma unroll
                for (int reg = 0; reg < 16; ++reg) {
                    const int r = rr + (reg & 3) + 8 * (reg >> 2);
                    rawt[r * 132 + cc] = acc[m][n][reg] + bias;
                }
            }
    }
    __syncthreads();
#pragma unroll
    for (int slot = 1; slot < 4; ++slot) {
        if (wk == slot) {
#pragma unroll
            for (int m = 0; m < 2; ++m)
#pragma unroll
                for (int n = 0; n < 2; ++n) {
                    const int cc = wn * 64 + n * 32 + ccol;
                    const int rr = wm * 64 + m * 32 + rowoff;
#pragma unroll
                    for (int reg = 0; reg < 16; ++reg) {
                        const int r = rr + (reg & 3) + 8 * (reg >> 2);
                        rawt[r * 132 + cc] += acc[m][n][reg];
                    }
                }
        }
        __syncthreads();
    }

    // ---- Phase 2: dense float4 store pass ----
    // per row: c in [0,192) -> sig float4; [192,224) -> raw float4.
    const float tl = expf(lt[0]);
    const int r0 = t >> 8;      // 0..3
    const int c  = t & 255;

    for (int pass = 0; pass < 32; ++pass) {
        const int r = pass * 4 + r0;
        const long long b = (long long)bm * 128 + r;
        if (c < 192) {
            const int u  = (2 * c) / 3;
            const int cs = c % 3;
            const unsigned short* srow = wsAs + b * KSIG + bn * 768;
            const float* strow = states + b * NUNITS + bn * 128;
            const ushort4 sin = *(const ushort4*)(srow + c * 4);
            const float e0 = bf2f(sin.x), e1 = bf2f(sin.y);
            const float e2 = bf2f(sin.z), e3 = bf2f(sin.w);
            float4 o;
            if (cs == 0) {                 // cols 6u+0..3: s0,s1,s2,s3
                const float d = rawt[r * 132 + u] - strow[u];
                o.x = e0 + d;
                o.y = e1 + tl;
                o.z = e2 + d  * (0.5f * d  + e0);
                o.w = e3 + tl * (0.5f * d  + e0);
            } else if (cs == 1) {          // cols 6u+4,5, 6(u+1)+0,1
                const float d  = rawt[r * 132 + u]     - strow[u];
                const float dn = rawt[r * 132 + u + 1] - strow[u + 1];
                const float s1 = bf2f(srow[u * 6 + 1]);
                o.x = e0 + d  * (0.5f * tl + s1);
                o.y = e1 + tl * (0.5f * tl + s1);
                o.z = e2 + dn;
                o.w = e3 + tl;
            } else {                       // cols 6u+2..5: s2,s3,s4,s5
                const float d = rawt[r * 132 + u] - strow[u];
                const unsigned int sv = *(const unsigned int*)(srow + u * 6);
                const float s0 = bf2f((unsigned short)(sv & 0xffffu));
                const float s1 = bf2f((unsigned short)(sv >> 16));
                o.x = e0 + d  * (0.5f * d  + s0);
                o.y = e1 + tl * (0.5f * d  + s0);
                o.z = e2 + d  * (0.5f * tl + s1);
                o.w = e3 + tl * (0.5f * tl + s1);
            }
            *(float4*)(out + b * OUTW + bn * 768 + c * 4) = o;
        } else if (c < 224) {
            const int cc = (c - 192) * 4;
            const float4 rv = *(const float4*)&rawt[r * 132 + cc];
            *(float4*)(out + b * OUTW + KSIG + bn * 128 + cc) = rv;
        }
    }
#undef STAGE
}

extern "C" void kernel_launch(void* const* d_in, const int* in_sizes, int n_in,
                              void* d_out, int out_size, void* d_ws, size_t ws_size,
                              hipStream_t stream) {
    const float* x      = (const float*)d_in[0];
    const float* sigs   = (const float*)d_in[1];
    const float* states = (const float*)d_in[2];
    const float* Ww     = (const float*)d_in[3];
    const float* Wb     = (const float*)d_in[4];
    const float* Uw     = (const float*)d_in[5];
    const float* Ub     = (const float*)d_in[6];
    const float* lt     = (const float*)d_in[7];
    float* out = (float*)d_out;

    unsigned short* ws = (unsigned short*)d_ws;
    hipLaunchKernelGGL(prepack, dim3(2048), dim3(256), 0, stream,
                       x, sigs, states, Ww, Uw, ws);
    hipLaunchKernelGGL(rsig_gemm, dim3(256), dim3(1024), 0, stream,
                       ws, states, Wb, Ub, lt, out);
}

// Round 11
// 172.588 us; speedup vs baseline: 1.0791x; 1.0374x over previous
//
#include <hip/hip_runtime.h>
#include <hip/hip_bf16.h>
#include <cmath>

// Problem constants
#define BATCH   4096
#define NUNITS  1024
#define INSIZE  512
#define SIGSZ   6
#define KSIG    (NUNITS * SIGSZ)          // 6144
#define SAVED   (KSIG + NUNITS)           // 7168
#define KTOT    (INSIZE + KSIG + NUNITS)  // 7680
#define OUTW    (NUNITS * (SIGSZ + 1))    // 7168
#define NKT     (KTOT / 64)               // 120

// Workspace layout (ushort elements)
#define WS_AX 0LL
#define WS_AS 2097152LL
#define WS_AT 27262976LL
#define WS_BW 31457280LL
#define WS_BU 31981568LL
#define WS_ELEMS 39321600LL
#define WS_BYTES (WS_ELEMS * 2)           // 78,643,200

typedef __attribute__((ext_vector_type(8)))  short bf16x8;
typedef __attribute__((ext_vector_type(8)))  unsigned short u16x8;
typedef __attribute__((ext_vector_type(4)))  float f32x4;
typedef __attribute__((ext_vector_type(16))) float f32x16;

__device__ __forceinline__ unsigned short f2bf(float f) {
    union { float f; unsigned int u; } c; c.f = f;
    unsigned int u = c.u;
    return (unsigned short)((u + 0x7FFFu + ((u >> 16) & 1u)) >> 16);  // RNE
}
__device__ __forceinline__ float bf2f(unsigned short h) {
    union { unsigned int u; float f; } c; c.u = ((unsigned int)h) << 16;
    return c.f;
}

// ---------------- prepass: fp32 -> packed bf16 in ws ----------------
__global__ __launch_bounds__(256)
void prepack(const float* __restrict__ x, const float* __restrict__ sigs,
             const float* __restrict__ states, const float* __restrict__ Ww,
             const float* __restrict__ Uw, unsigned short* __restrict__ ws)
{
    const long long stride = (long long)gridDim.x * blockDim.x;
    for (long long p = (long long)blockIdx.x * blockDim.x + threadIdx.x;
         p < 4915200LL; p += stride) {
        const float* src; unsigned short* dst; long long o;
        if (p < 262144LL)       { src = x;      dst = ws + WS_AX; o = p; }
        else if (p < 3407872LL) { src = sigs;   dst = ws + WS_AS; o = p - 262144LL; }
        else if (p < 3932160LL) { src = states; dst = ws + WS_AT; o = p - 3407872LL; }
        else if (p < 3997696LL) { src = Ww;     dst = ws + WS_BW; o = p - 3932160LL; }
        else                    { src = Uw;     dst = ws + WS_BU; o = p - 3997696LL; }
        const f32x4 v0 = __builtin_nontemporal_load((const f32x4*)(src + o * 8));
        const f32x4 v1 = __builtin_nontemporal_load((const f32x4*)(src + o * 8) + 1);
        u16x8 h;
        h[0] = f2bf(v0[0]); h[1] = f2bf(v0[1]); h[2] = f2bf(v0[2]); h[3] = f2bf(v0[3]);
        h[4] = f2bf(v1[0]); h[5] = f2bf(v1[1]); h[6] = f2bf(v1[2]); h[7] = f2bf(v1[3]);
        *(u16x8*)(dst + o * 8) = h;
    }
}

// ---------------- main GEMM + fused sigjoin ----------------
// R8 pipeline skeleton + R10 mfma_32x32x16 read savings:
// 128x128 tile, BK=64, 1024 threads = 16 waves: 2(M) x 2(N) x 4(K16-slot).
// Wave tile 64x64 per K16: 2 A + 2 B ds_read_b128 -> 4 mfma_32x32x16.
// LDS packing per tile (16 KB A + 16 KB B): 64 double-rows x 16 slots x 16B.
//   key = (kblk<<1)|(row&1), stored at slot s = key ^ (drow&15)  (bijective,
//   bank-uniform for 32-row column reads; same involution on staging source).
// Ring-3 (96 KB), counted vmcnt(2), ONE raw barrier/iter, STAGE(kt+2) after it.
// Epilogue: K-split-4 merge into padded 128x132 fp32 LDS tile, dense float4
// store pass (full lines, no RMW).
#define GLD_LDS(G, L) __builtin_amdgcn_global_load_lds(                        \
        (const __attribute__((address_space(1))) unsigned int*)(G),           \
        (__attribute__((address_space(3))) unsigned int*)(L), 16, 0, 0)

__global__ __launch_bounds__(1024, 1)
void rsig_gemm(const unsigned short* __restrict__ ws,
               const float* __restrict__ states,
               const float* __restrict__ Wb,
               const float* __restrict__ Ub,
               const float* __restrict__ lt,
               float* __restrict__ out)
{
    // ring buffer: A [0,8192), B [8192,16384) ushorts per 16K-slot (32 KB)
    __shared__ unsigned short lds[3 * 16384];   // 96 KB

    const int t  = threadIdx.x;
    const int bn = blockIdx.x & 7;   // natural round-robin: same bn -> same XCD
    const int bm = blockIdx.x >> 3;  // 0..31

    const int lane = t & 63;
    const int w    = t >> 6;        // 0..15
    const int wm   = w >> 3;        // M half
    const int wn   = (w >> 2) & 1;  // N half
    const int wk   = w & 3;         // K16 slot within BK=64
    const int lrow = lane & 31;
    const int lkh  = lane >> 5;     // k-half of the K16 (8 bf16 each)
    const int kbw  = wk * 2 + lkh;  // k-block 0..7 (16B units within K64)

    const unsigned short* wsAx = ws + WS_AX;
    const unsigned short* wsAs = ws + WS_AS;
    const unsigned short* wsAt = ws + WS_AT;
    const unsigned short* wsBw = ws + WS_BW;
    const unsigned short* wsBu = ws + WS_BU;

    // staging decomposition: wave w writes double-rows [w*4, w*4+4), lane l ->
    // D = w*4 + (l>>4), slot sS = l&15; inverse map to source (row, kblk):
    const int sD   = w * 4 + (lane >> 4);
    const int sKey = (lane & 15) ^ (sD & 15);
    const int sR   = sD * 2 + (sKey & 1);     // source row 0..127 within tile
    const int sKb  = sKey >> 1;               // source k-block 0..7

    f32x16 acc[2][2];
#pragma unroll
    for (int m = 0; m < 2; ++m)
#pragma unroll
        for (int n = 0; n < 2; ++n)
            acc[m][n] = (f32x16)0.f;

    // 2 gld_lds per wave per STAGE (1 A + 1 B)
#define STAGE(BUF, KT)                                                                   \
    {                                                                                    \
        const int kt_ = (KT);                                                            \
        const unsigned short* abase; int astr; long long koff;                           \
        if (kt_ < 8)        { abase = wsAx; astr = INSIZE; koff = kt_ * 64LL; }          \
        else if (kt_ < 104) { abase = wsAs; astr = KSIG;   koff = kt_ * 64LL - 512; }    \
        else                { abase = wsAt; astr = NUNITS; koff = kt_ * 64LL - 6656; }   \
        const unsigned short* bbase; int bstr; long long koffb;                          \
        if (kt_ < 8)        { bbase = wsBw; bstr = INSIZE; koffb = kt_ * 64LL; }         \
        else                { bbase = wsBu; bstr = SAVED;  koffb = kt_ * 64LL - 512; }   \
        unsigned short* base = &lds[(BUF) * 16384];                                      \
        GLD_LDS(abase + (size_t)(bm * 128 + sR) * astr + koff  + sKb * 8, base + w * 512);        \
        GLD_LDS(bbase + (size_t)(bn * 128 + sR) * bstr + koffb + sKb * 8, base + 8192 + w * 512); \
    }

    // Prologue: 2 tiles in flight (4 loads/wave outstanding)
    STAGE(0, 0);
    STAGE(1, 1);

    int cur = 0;
    for (int kt = 0; kt < NKT; ++kt) {
        // counted wait: tile kt's 2 loads land; tile kt+1's 2 stay in flight
        if (kt < NKT - 1) { asm volatile("s_waitcnt vmcnt(2)" ::: "memory"); }
        else              { asm volatile("s_waitcnt vmcnt(0)" ::: "memory"); }
        __builtin_amdgcn_s_barrier();
        __builtin_amdgcn_sched_barrier(0);

        if (kt + 2 < NKT) {
            int nb = cur + 2; if (nb >= 3) nb -= 3;
            STAGE(nb, kt + 2);   // overwrites buf[(kt-1)%3]: readers done pre-barrier
        }

        {
            const unsigned short* aT = &lds[cur * 16384];
            const unsigned short* bT = aT + 8192;
            bf16x8 af[2], bfr[2];
#pragma unroll
            for (int m = 0; m < 2; ++m) {
                const int R = wm * 64 + m * 32 + lrow;
                const int D = R >> 1;
                const int s = ((kbw << 1) | (R & 1)) ^ (D & 15);
                af[m] = *(const bf16x8*)&aT[D * 128 + s * 8];
            }
#pragma unroll
            for (int n = 0; n < 2; ++n) {
                const int R = wn * 64 + n * 32 + lrow;
                const int D = R >> 1;
                const int s = ((kbw << 1) | (R & 1)) ^ (D & 15);
                bfr[n] = *(const bf16x8*)&bT[D * 128 + s * 8];
            }
#pragma unroll
            for (int m = 0; m < 2; ++m)
#pragma unroll
                for (int n = 0; n < 2; ++n)
                    acc[m][n] = __builtin_amdgcn_mfma_f32_32x32x16_bf16(
                        af[m], bfr[n], acc[m][n], 0, 0, 0);
        }

        cur = (cur == 2) ? 0 : cur + 1;
    }

    __syncthreads();   // everyone done reading LDS before rawt reuse

    // ---- Phase 1: raw(+bias) -> padded LDS tile; K-split-4 merged ----
    // 32x32 C/D layout: col = lane&31, row = (reg&3) + 8*(reg>>2) + 4*(lane>>5)
    float* rawt = (float*)lds;            // 128 rows x 132 floats (67.6 KB)
    const int ccol   = lane & 31;
    const int rowoff = 4 * lkh;
    if (wk == 0) {
#pragma unroll
        for (int m = 0; m < 2; ++m)
#pragma unroll
            for (int n = 0; n < 2; ++n) {
                const int cc = wn * 64 + n * 32 + ccol;
                const int rr = wm * 64 + m * 32 + rowoff;
                const float bias = Wb[bn * 128 + cc] + Ub[bn * 128 + cc];
#pragma unroll
                for (int reg = 0; reg < 16; ++reg) {
                    const int r = rr + (reg & 3) + 8 * (reg >> 2);
                    rawt[r * 132 + cc] = acc[m][n][reg] + bias;
                }
            }
    }
    __syncthreads();
#pragma unroll
    for (int slot = 1; slot < 4; ++slot) {
        if (wk == slot) {
#pragma unroll
            for (int m = 0; m < 2; ++m)
#pragma unroll
                for (int n = 0; n < 2; ++n) {
                    const int cc = wn * 64 + n * 32 + ccol;
                    const int rr = wm * 64 + m * 32 + rowoff;
#pragma unroll
                    for (int reg = 0; reg < 16; ++reg) {
                        const int r = rr + (reg & 3) + 8 * (reg >> 2);
                        rawt[r * 132 + cc] += acc[m][n][reg];
                    }
                }
        }
        __syncthreads();
    }

    // ---- Phase 2: dense float4 store pass ----
    // per row: c in [0,192) -> sig float4; [192,224) -> raw float4.
    const float tl = expf(lt[0]);
    const int r0 = t >> 8;      // 0..3
    const int c  = t & 255;

    for (int pass = 0; pass < 32; ++pass) {
        const int r = pass * 4 + r0;
        const long long b = (long long)bm * 128 + r;
        if (c < 192) {
            const int u  = (2 * c) / 3;
            const int cs = c % 3;
            const unsigned short* srow = wsAs + b * KSIG + bn * 768;
            const float* strow = states + b * NUNITS + bn * 128;
            const ushort4 sin = *(const ushort4*)(srow + c * 4);
            const float e0 = bf2f(sin.x), e1 = bf2f(sin.y);
            const float e2 = bf2f(sin.z), e3 = bf2f(sin.w);
            float4 o;
            if (cs == 0) {                 // cols 6u+0..3: s0,s1,s2,s3
                const float d = rawt[r * 132 + u] - strow[u];
                o.x = e0 + d;
                o.y = e1 + tl;
                o.z = e2 + d  * (0.5f * d  + e0);
                o.w = e3 + tl * (0.5f * d  + e0);
            } else if (cs == 1) {          // cols 6u+4,5, 6(u+1)+0,1
                const float d  = rawt[r * 132 + u]     - strow[u];
                const float dn = rawt[r * 132 + u + 1] - strow[u + 1];
                const float s1 = bf2f(srow[u * 6 + 1]);
                o.x = e0 + d  * (0.5f * tl + s1);
                o.y = e1 + tl * (0.5f * tl + s1);
                o.z = e2 + dn;
                o.w = e3 + tl;
            } else {                       // cols 6u+2..5: s2,s3,s4,s5
                const float d = rawt[r * 132 + u] - strow[u];
                const unsigned int sv = *(const unsigned int*)(srow + u * 6);
                const float s0 = bf2f((unsigned short)(sv & 0xffffu));
                const float s1 = bf2f((unsigned short)(sv >> 16));
                o.x = e0 + d  * (0.5f * d  + s0);
                o.y = e1 + tl * (0.5f * d  + s0);
                o.z = e2 + d  * (0.5f * tl + s1);
                o.w = e3 + tl * (0.5f * tl + s1);
            }
            *(float4*)(out + b * OUTW + bn * 768 + c * 4) = o;
        } else if (c < 224) {
            const int cc = (c - 192) * 4;
            const float4 rv = *(const float4*)&rawt[r * 132 + cc];
            *(float4*)(out + b * OUTW + KSIG + bn * 128 + cc) = rv;
        }
    }
#undef STAGE
}

extern "C" void kernel_launch(void* const* d_in, const int* in_sizes, int n_in,
                              void* d_out, int out_size, void* d_ws, size_t ws_size,
                              hipStream_t stream) {
    const float* x      = (const float*)d_in[0];
    const float* sigs   = (const float*)d_in[1];
    const float* states = (const float*)d_in[2];
    const float* Ww     = (const float*)d_in[3];
    const float* Wb     = (const float*)d_in[4];
    const float* Uw     = (const float*)d_in[5];
    const float* Ub     = (const float*)d_in[6];
    const float* lt     = (const float*)d_in[7];
    float* out = (float*)d_out;

    unsigned short* ws = (unsigned short*)d_ws;
    hipLaunchKernelGGL(prepack, dim3(2048), dim3(256), 0, stream,
                       x, sigs, states, Ww, Uw, ws);
    hipLaunchKernelGGL(rsig_gemm, dim3(256), dim3(1024), 0, stream,
                       ws, states, Wb, Ub, lt, out);
}